// Round 1
// 1183.377 us; speedup vs baseline: 1.0678x; 1.0678x over previous
//
#include <hip/hip_runtime.h>

// ---------------------------------------------------------------------------
// WindowAttention fused kernel for MI355X (gfx950) — in-register attention.
// x[4096,64,192] -> qkv -> 6-head windowed attention (+rel-bias +mask)
// -> softmax (attn is output 1) -> PV -> proj (+bias) (out is output 0)
//
// One block per window, 6 waves = 1 wave per head.
// KEY IDEA: GEMM1 computes Q,K with SWAPPED MFMA operands (A=W, B=x) so the
// C-layout (row = quad*4+r at head-dim, col = c16 at token) is *directly* the
// A/B fragment layout of v_mfma_f32_16x16x16_bf16 (k = quad*4+e). The whole
// QK^T -> softmax -> PV chain then runs with zero LDS and zero cross-lane
// data movement except 16 shfl_xor in softmax. LDS holds only the 64x200
// bf16 ctx tile for the cross-head proj GEMM (25.6 KB vs 76.8 KB before),
// so 2 blocks/CU become resident (was 1; unified VGPR+AGPR ~180 and 76.8KB
// LDS both capped us at 6 waves/CU).
// ---------------------------------------------------------------------------

typedef short bf16x8 __attribute__((ext_vector_type(8)));
typedef short bf16x4 __attribute__((ext_vector_type(4)));
typedef float f32x4  __attribute__((ext_vector_type(4)));

#define W2_OFF   (576*192*2)                 // bytes
#define BM_OFF   (W2_OFF + 192*192*2)
#define BM_ELEMS (64*6*4*4*64*4)             // [w][h][jt][it][lane][r] ushort
#define WS_NEEDED ((size_t)BM_OFF + (size_t)BM_ELEMS*2)

#define MFMA32(A,B,C) __builtin_amdgcn_mfma_f32_16x16x32_bf16(A, B, C, 0, 0, 0)
#define MFMA16(A,B,C) __builtin_amdgcn_mfma_f32_16x16x16bf16_1k(A, B, C, 0, 0, 0)

static __device__ __forceinline__ unsigned bfr(float x) {   // fp32->bf16 RNE
    unsigned u = __float_as_uint(x);
    return (u + 0x7FFFu + ((u >> 16) & 1u)) >> 16;
}
static __device__ __forceinline__ unsigned pkt(float a, float b) { // trunc pack
    return (__float_as_uint(a) >> 16) | (__float_as_uint(b) & 0xFFFF0000u);
}
static __device__ __forceinline__ unsigned pk2(float a, float b) { // RNE pack
    return bfr(a) | (bfr(b) << 16);
}
static __device__ __forceinline__ float b2f(unsigned short s) {
    return __uint_as_float(((unsigned)s) << 16);
}

// ---------------- prep: weights fp32 -> bf16 -------------------------------
extern "C" __global__ void wa_prep_w(const float* __restrict__ qkv_w,
                                     const float* __restrict__ proj_w,
                                     unsigned short* __restrict__ w1,
                                     unsigned short* __restrict__ w2) {
    const int tot = 576*192 + 192*192;
    for (int i = blockIdx.x * blockDim.x + threadIdx.x; i < tot;
         i += gridDim.x * blockDim.x) {
        if (i < 576*192) w1[i] = (unsigned short)bfr(qkv_w[i]);
        else             w2[i - 576*192] = (unsigned short)bfr(proj_w[i - 576*192]);
    }
}

// ---------------- prep: fused (rel-bias + mask) table, S^T-layout swizzled -
// bm[w][h][jt][it][lane][r] = mask[w][i][j] + bias[h][i][j] with
// i = it*16 + (lane&15), j = jt*16 + (lane>>4)*4 + r  (matches S^T C-layout)
extern "C" __global__ void wa_prep_bm(const float* __restrict__ mask,
                                      const float* __restrict__ table,
                                      unsigned short* __restrict__ bm) {
    for (int i = blockIdx.x * blockDim.x + threadIdx.x; i < BM_ELEMS;
         i += gridDim.x * blockDim.x) {
        const int r    = i & 3;
        const int lane = (i >> 2) & 63;
        const int it   = (i >> 8) & 3;
        const int jt   = (i >> 10) & 3;
        const int wh   = i >> 12;          // w*6 + h
        const int h    = wh % 6;
        const int w    = wh / 6;
        const int quad = lane >> 4, c16 = lane & 15;
        const int ii = it*16 + c16;              // query token i
        const int jj = jt*16 + quad*4 + r;       // key token j
        const int di = (ii >> 3) - (jj >> 3) + 7;
        const int dj = (ii & 7) - (jj & 7) + 7;
        const float v = mask[(w*64 + ii)*64 + jj] + table[(di*15 + dj)*6 + h];
        bm[i] = (unsigned short)bfr(v);
    }
}

// ---------------- main fused kernel ----------------------------------------
extern "C" __global__ __launch_bounds__(384, 3)
void wa_main(const float* __restrict__ x,
             const float* __restrict__ qkv_b,
             const float* __restrict__ proj_b,
             const unsigned short* __restrict__ w1,
             const unsigned short* __restrict__ w2,
             const unsigned short* __restrict__ bm,
             float* __restrict__ out,
             float* __restrict__ attn_out) {
    // LDS: ONLY the cross-wave ctx tile [64 tok][200 (192+pad)] bf16 = 25.6KB
    __shared__ __align__(16) unsigned short smem[64 * 200];

    const int tid  = threadIdx.x;
    const int h    = tid >> 6;      // wave id == head
    const int lane = tid & 63;
    const int quad = lane >> 4;
    const int c16  = lane & 15;
    const int b    = blockIdx.x;

    // ================= GEMM1: qkv = x @ W1^T + b ===========================
    // Q,K SWAPPED (A=W, B=x): acc lane holds (d = mo*16+quad*4+r, tok = t*16+c16)
    // V unswapped (A=x, B=W): acc lane holds (tok = t*16+quad*4+r, d = dt*16+c16)
    f32x4 accQ[2][4] = {}; f32x4 accK[2][4] = {}; f32x4 accV[4][2] = {};
    #pragma unroll
    for (int ks = 0; ks < 6; ++ks) {
        const int c0 = ks*32 + quad*8;
        bf16x8 xf[4];
        #pragma unroll
        for (int t = 0; t < 4; ++t) {
            const float4* xp =
                (const float4*)(x + ((size_t)b*64 + t*16 + c16)*192 + c0);
            const float4 a = xp[0], c = xp[1];
            union { bf16x8 v; unsigned u[4]; } uf;
            uf.u[0] = pkt(a.x, a.y); uf.u[1] = pkt(a.z, a.w);
            uf.u[2] = pkt(c.x, c.y); uf.u[3] = pkt(c.z, c.w);
            xf[t] = uf.v;
        }
        #pragma unroll
        for (int mo = 0; mo < 2; ++mo) {
            const int o = h*32 + mo*16 + c16;
            const bf16x8 wq = *(const bf16x8*)(w1 + (size_t)o*192 + c0);
            const bf16x8 wk = *(const bf16x8*)(w1 + (size_t)(o + 192)*192 + c0);
            #pragma unroll
            for (int t = 0; t < 4; ++t) {
                accQ[mo][t] = MFMA32(wq, xf[t], accQ[mo][t]);   // A=W, B=x
                accK[mo][t] = MFMA32(wk, xf[t], accK[mo][t]);
            }
        }
        #pragma unroll
        for (int dt = 0; dt < 2; ++dt) {
            const bf16x8 wv =
                *(const bf16x8*)(w1 + (size_t)(384 + h*32 + dt*16 + c16)*192 + c0);
            #pragma unroll
            for (int t = 0; t < 4; ++t)
                accV[t][dt] = MFMA32(xf[t], wv, accV[t][dt]);   // A=x, B=W
        }
    }

    // ---- epilogue: +bias (SCALE folded into Q), pack to K=16 fragments ----
    float bq[2][4], bk[2][4];
    #pragma unroll
    for (int mo = 0; mo < 2; ++mo)
        #pragma unroll
        for (int r = 0; r < 4; ++r) {
            const int o = h*32 + mo*16 + quad*4 + r;
            bq[mo][r] = qkv_b[o];
            bk[mo][r] = qkv_b[o + 192];
        }
    const float bv0 = qkv_b[384 + h*32 + c16];
    const float bv1 = qkv_b[384 + h*32 + 16 + c16];

    union U4 { bf16x4 v; unsigned u[2]; };
    const float SC = 0.17677669529663687f;          // 1/sqrt(32)

    bf16x4 qf[4][2], kf[4][2], vf[4][2];
    #pragma unroll
    for (int t = 0; t < 4; ++t)
        #pragma unroll
        for (int mo = 0; mo < 2; ++mo) {
            U4 uq, uk;
            uq.u[0] = pk2((accQ[mo][t][0] + bq[mo][0]) * SC,
                          (accQ[mo][t][1] + bq[mo][1]) * SC);
            uq.u[1] = pk2((accQ[mo][t][2] + bq[mo][2]) * SC,
                          (accQ[mo][t][3] + bq[mo][3]) * SC);
            qf[t][mo] = uq.v;                       // B-frag: Q[i=t*16+c16][d]
            uk.u[0] = pk2(accK[mo][t][0] + bk[mo][0], accK[mo][t][1] + bk[mo][1]);
            uk.u[1] = pk2(accK[mo][t][2] + bk[mo][2], accK[mo][t][3] + bk[mo][3]);
            kf[t][mo] = uk.v;                       // A-frag: K[j=t*16+c16][d]
        }
    #pragma unroll
    for (int j4 = 0; j4 < 4; ++j4)
        #pragma unroll
        for (int dt = 0; dt < 2; ++dt) {
            const float bv = dt ? bv1 : bv0;
            U4 uv;
            uv.u[0] = pk2(accV[j4][dt][0] + bv, accV[j4][dt][1] + bv);
            uv.u[1] = pk2(accV[j4][dt][2] + bv, accV[j4][dt][3] + bv);
            vf[j4][dt] = uv.v;                      // B-frag: V[j][d=dt*16+c16]
        }

    // ================= S^T = K @ Q^T  (two K=16 MFMAs per 16x16 tile) ======
    // S^T C-layout: lane holds (j = jt*16+quad*4+r, i = it*16+c16)
    const unsigned short* bmb = bm + ((size_t)(b & 63)*6 + h)*4096;
    ushort4 bmv[4][4];
    #pragma unroll
    for (int jt = 0; jt < 4; ++jt)
        #pragma unroll
        for (int it = 0; it < 4; ++it)
            bmv[jt][it] = *(const ushort4*)(bmb + (jt*4 + it)*256 + lane*4);

    f32x4 s[4][4];
    #pragma unroll
    for (int jt = 0; jt < 4; ++jt)
        #pragma unroll
        for (int it = 0; it < 4; ++it) {
            f32x4 z = {0.f, 0.f, 0.f, 0.f};
            z        = MFMA16(kf[jt][0], qf[it][0], z);
            s[jt][it] = MFMA16(kf[jt][1], qf[it][1], z);
        }
    // + (rel bias + window mask), pre-swizzled to S^T layout
    #pragma unroll
    for (int jt = 0; jt < 4; ++jt)
        #pragma unroll
        for (int it = 0; it < 4; ++it) {
            s[jt][it][0] += b2f(bmv[jt][it].x);
            s[jt][it][1] += b2f(bmv[jt][it].y);
            s[jt][it][2] += b2f(bmv[jt][it].z);
            s[jt][it][3] += b2f(bmv[jt][it].w);
        }

    // ================= softmax over j (rows of S^T) ========================
    // per lane: 16 in-register values per i, then 2 shfl_xor across quads
    const float L2E = 1.4426950408889634f;
    #pragma unroll
    for (int it = 0; it < 4; ++it) {
        float m0 = s[0][it][0];
        #pragma unroll
        for (int jt = 0; jt < 4; ++jt)
            #pragma unroll
            for (int r = 0; r < 4; ++r)
                m0 = fmaxf(m0, s[jt][it][r]);
        m0 = fmaxf(m0, __shfl_xor(m0, 16));
        m0 = fmaxf(m0, __shfl_xor(m0, 32));
        float sum = 0.f;
        #pragma unroll
        for (int jt = 0; jt < 4; ++jt)
            #pragma unroll
            for (int r = 0; r < 4; ++r) {
                const float e = exp2f((s[jt][it][r] - m0) * L2E);
                s[jt][it][r] = e;
                sum += e;
            }
        sum += __shfl_xor(sum, 16);
        sum += __shfl_xor(sum, 32);
        const float rinv = 1.0f / sum;
        #pragma unroll
        for (int jt = 0; jt < 4; ++jt)
            #pragma unroll
            for (int r = 0; r < 4; ++r)
                s[jt][it][r] *= rinv;
    }

    // ================= attn store (float4: lane holds 4 consecutive j) ====
    float* aob = attn_out + ((size_t)b*6 + h)*4096;
    #pragma unroll
    for (int it = 0; it < 4; ++it)
        #pragma unroll
        for (int jt = 0; jt < 4; ++jt)
            *(f32x4*)(aob + (it*16 + c16)*64 + jt*16 + quad*4) = s[jt][it];

    // ================= ctx = P @ V (P packed straight from S^T regs) =======
    f32x4 accO[4][2] = {};
    #pragma unroll
    for (int j4 = 0; j4 < 4; ++j4)
        #pragma unroll
        for (int it = 0; it < 4; ++it) {
            U4 p;
            p.u[0] = pk2(s[j4][it][0], s[j4][it][1]);
            p.u[1] = pk2(s[j4][it][2], s[j4][it][3]);
            accO[it][0] = MFMA16(p.v, vf[j4][0], accO[it][0]);
            accO[it][1] = MFMA16(p.v, vf[j4][1], accO[it][1]);
        }

    // ================= ctx -> shared LDS (cross-wave), then proj ===========
    #pragma unroll
    for (int it = 0; it < 4; ++it)
        #pragma unroll
        for (int dt = 0; dt < 2; ++dt)
            #pragma unroll
            for (int r = 0; r < 4; ++r)
                smem[(it*16 + quad*4 + r)*200 + h*32 + dt*16 + c16] =
                    (unsigned short)bfr(accO[it][dt][r]);
    __syncthreads();

    f32x4 accU[4][2] = {};
    #pragma unroll
    for (int ks = 0; ks < 6; ++ks) {
        const int c0 = ks*32 + quad*8;
        bf16x8 cf[4];
        #pragma unroll
        for (int mt = 0; mt < 4; ++mt)
            cf[mt] = *(const bf16x8*)&smem[(mt*16 + c16)*200 + c0];
        #pragma unroll
        for (int ntl = 0; ntl < 2; ++ntl) {
            const bf16x8 wf =
                *(const bf16x8*)(w2 + (size_t)((h*2 + ntl)*16 + c16)*192 + c0);
            #pragma unroll
            for (int mt = 0; mt < 4; ++mt)
                accU[mt][ntl] = MFMA32(cf[mt], wf, accU[mt][ntl]);
        }
    }
    #pragma unroll
    for (int ntl = 0; ntl < 2; ++ntl) {
        const int o = (h*2 + ntl)*16 + c16;
        const float pb2 = proj_b[o];
        #pragma unroll
        for (int mt = 0; mt < 4; ++mt)
            #pragma unroll
            for (int r = 0; r < 4; ++r)
                out[((size_t)b*64 + mt*16 + quad*4 + r)*192 + o] =
                    accU[mt][ntl][r] + pb2;
    }
}

// ---------------------------------------------------------------------------
extern "C" void kernel_launch(void* const* d_in, const int* in_sizes, int n_in,
                              void* d_out, int out_size, void* d_ws, size_t ws_size,
                              hipStream_t stream) {
    const float* x      = (const float*)d_in[0];
    const float* mask   = (const float*)d_in[1];
    const float* qkv_w  = (const float*)d_in[2];
    const float* qkv_b  = (const float*)d_in[3];
    const float* proj_w = (const float*)d_in[4];
    const float* proj_b = (const float*)d_in[5];
    const float* table  = (const float*)d_in[6];

    if (ws_size < WS_NEEDED) return;   // ~3.5 MB scratch required

    unsigned short* w1 = (unsigned short*)d_ws;
    unsigned short* w2 = (unsigned short*)((char*)d_ws + W2_OFF);
    unsigned short* bm = (unsigned short*)((char*)d_ws + BM_OFF);

    float* out  = (float*)d_out;
    float* attn = out + (size_t)4096 * 64 * 192;

    hipLaunchKernelGGL(wa_prep_w,  dim3(576),  dim3(256), 0, stream,
                       qkv_w, proj_w, w1, w2);
    hipLaunchKernelGGL(wa_prep_bm, dim3(1536), dim3(256), 0, stream,
                       mask, table, bm);
    hipLaunchKernelGGL(wa_main, dim3(4096), dim3(384), 0, stream,
                       x, qkv_b, proj_b, w1, w2, bm, out, attn);
}

// Round 2
// 939.011 us; speedup vs baseline: 1.3456x; 1.2602x over previous
//
#include <hip/hip_runtime.h>

// ---------------------------------------------------------------------------
// WindowAttention fused kernel for MI355X (gfx950) — in-register attention,
// register-dieted for 2 blocks/CU occupancy.
// x[4096,64,192] -> qkv -> 6-head windowed attention (+rel-bias +mask)
// -> softmax (attn is output 1) -> PV -> proj (+bias) (out is output 0)
//
// One block per window, 6 waves = 1 wave per head.
//  * x tile is staged once, cooperatively, into LDS as bf16 [64][200].
//  * GEMM1 runs as two passes (Q+K, then V) over the LDS tile so at most
//    64 accumulator regs are live at once (was 96 -> total ~180 regs/wave
//    -> 2 waves/SIMD -> 1 block/CU; now ~140 -> 3 waves/SIMD -> 2 blocks).
//  * Q,K computed with SWAPPED MFMA operands (A=W, B=x) so the C-layout
//    (d at quad*4+r, token at c16) is directly the A/B fragment layout of
//    v_mfma_f32_16x16x16bf16_1k. QK^T -> softmax -> PV runs entirely in
//    registers (no LDS, only 4 shfl_xor per row-group in softmax).
//  * rel-bias+mask table pre-swizzled to the S^T C-layout, loaded per-jt
//    (8 regs live) and added straight to the S accumulators.
// ---------------------------------------------------------------------------

typedef short bf16x8 __attribute__((ext_vector_type(8)));
typedef short bf16x4 __attribute__((ext_vector_type(4)));
typedef float f32x4  __attribute__((ext_vector_type(4)));

#define W2_OFF   (576*192*2)                 // bytes
#define BM_OFF   (W2_OFF + 192*192*2)
#define BM_ELEMS (64*6*4*4*64*4)             // [w][h][jt][it][lane][r] ushort
#define WS_NEEDED ((size_t)BM_OFF + (size_t)BM_ELEMS*2)

#define MFMA32(A,B,C) __builtin_amdgcn_mfma_f32_16x16x32_bf16(A, B, C, 0, 0, 0)
#define MFMA16(A,B,C) __builtin_amdgcn_mfma_f32_16x16x16bf16_1k(A, B, C, 0, 0, 0)

static __device__ __forceinline__ unsigned bfr(float x) {   // fp32->bf16 RNE
    unsigned u = __float_as_uint(x);
    return (u + 0x7FFFu + ((u >> 16) & 1u)) >> 16;
}
static __device__ __forceinline__ unsigned pkt(float a, float b) { // trunc pack
    return (__float_as_uint(a) >> 16) | (__float_as_uint(b) & 0xFFFF0000u);
}
static __device__ __forceinline__ unsigned pk2(float a, float b) { // RNE pack
    return bfr(a) | (bfr(b) << 16);
}
static __device__ __forceinline__ float b2f(unsigned short s) {
    return __uint_as_float(((unsigned)s) << 16);
}

// ---------------- prep: weights fp32 -> bf16 -------------------------------
extern "C" __global__ void wa_prep_w(const float* __restrict__ qkv_w,
                                     const float* __restrict__ proj_w,
                                     unsigned short* __restrict__ w1,
                                     unsigned short* __restrict__ w2) {
    const int tot = 576*192 + 192*192;
    for (int i = blockIdx.x * blockDim.x + threadIdx.x; i < tot;
         i += gridDim.x * blockDim.x) {
        if (i < 576*192) w1[i] = (unsigned short)bfr(qkv_w[i]);
        else             w2[i - 576*192] = (unsigned short)bfr(proj_w[i - 576*192]);
    }
}

// ---------------- prep: fused (rel-bias + mask) table, S^T-layout swizzled -
// bm[w][h][jt][it][lane][r] = mask[w][i][j] + bias[h][i][j] with
// i = it*16 + (lane&15), j = jt*16 + (lane>>4)*4 + r  (matches S^T C-layout)
extern "C" __global__ void wa_prep_bm(const float* __restrict__ mask,
                                      const float* __restrict__ table,
                                      unsigned short* __restrict__ bm) {
    for (int i = blockIdx.x * blockDim.x + threadIdx.x; i < BM_ELEMS;
         i += gridDim.x * blockDim.x) {
        const int r    = i & 3;
        const int lane = (i >> 2) & 63;
        const int it   = (i >> 8) & 3;
        const int jt   = (i >> 10) & 3;
        const int wh   = i >> 12;          // w*6 + h
        const int h    = wh % 6;
        const int w    = wh / 6;
        const int quad = lane >> 4, c16 = lane & 15;
        const int ii = it*16 + c16;              // query token i
        const int jj = jt*16 + quad*4 + r;       // key token j
        const int di = (ii >> 3) - (jj >> 3) + 7;
        const int dj = (ii & 7) - (jj & 7) + 7;
        const float v = mask[(w*64 + ii)*64 + jj] + table[(di*15 + dj)*6 + h];
        bm[i] = (unsigned short)bfr(v);
    }
}

// ---------------- main fused kernel ----------------------------------------
extern "C" __global__ __launch_bounds__(384, 3)
void wa_main(const float* __restrict__ x,
             const float* __restrict__ qkv_b,
             const float* __restrict__ proj_b,
             const unsigned short* __restrict__ w1,
             const unsigned short* __restrict__ w2,
             const unsigned short* __restrict__ bm,
             float* __restrict__ out,
             float* __restrict__ attn_out) {
    // LDS: x tile bf16 [64][200] (25.6KB) + ctx tile bf16 [64][200] (25.6KB)
    __shared__ __align__(16) unsigned short xs[64 * 200];
    __shared__ __align__(16) unsigned short cs[64 * 200];

    const int tid  = threadIdx.x;
    const int h    = tid >> 6;      // wave id == head
    const int lane = tid & 63;
    const int quad = lane >> 4;
    const int c16  = lane & 15;
    const int b    = blockIdx.x;

    // ========== stage x -> LDS (cooperative, once per block) ===============
    // 64 rows x 192 cols fp32 -> bf16 [64][200]. 1536 8-float chunks/384 thr.
    #pragma unroll
    for (int it4 = 0; it4 < 4; ++it4) {
        const int i   = tid + it4*384;
        const int row = i / 24, c8 = i % 24;
        const float4* xp = (const float4*)(x + ((size_t)b*64 + row)*192 + c8*8);
        const float4 a = xp[0], c = xp[1];
        union { bf16x8 v; unsigned u[4]; } uf;
        uf.u[0] = pkt(a.x, a.y); uf.u[1] = pkt(a.z, a.w);
        uf.u[2] = pkt(c.x, c.y); uf.u[3] = pkt(c.z, c.w);
        *(bf16x8*)&xs[row*200 + c8*8] = uf.v;
    }
    __syncthreads();

    union U4 { bf16x4 v; unsigned u[2]; };
    const float SC = 0.17677669529663687f;          // 1/sqrt(32)

    // ========== GEMM1 pass 1: Q,K (SWAPPED: A=W, B=x) ======================
    // acc lane holds (d = mo*16+quad*4+r, tok = t*16+c16)
    bf16x4 qf[4][2], kf[4][2], vf[4][2];
    {
        f32x4 accQ[2][4] = {}; f32x4 accK[2][4] = {};
        #pragma unroll
        for (int ks = 0; ks < 6; ++ks) {
            const int c0 = ks*32 + quad*8;
            bf16x8 xf[4];
            #pragma unroll
            for (int t = 0; t < 4; ++t)
                xf[t] = *(const bf16x8*)&xs[(t*16 + c16)*200 + c0];
            #pragma unroll
            for (int mo = 0; mo < 2; ++mo) {
                const int o = h*32 + mo*16 + c16;
                const bf16x8 wq = *(const bf16x8*)(w1 + (size_t)o*192 + c0);
                const bf16x8 wk = *(const bf16x8*)(w1 + (size_t)(o + 192)*192 + c0);
                #pragma unroll
                for (int t = 0; t < 4; ++t) {
                    accQ[mo][t] = MFMA32(wq, xf[t], accQ[mo][t]);
                    accK[mo][t] = MFMA32(wk, xf[t], accK[mo][t]);
                }
            }
        }
        // +bias (SCALE folded into Q), pack to K=16 fragments
        #pragma unroll
        for (int mo = 0; mo < 2; ++mo) {
            const float4 bq4 = *(const float4*)(qkv_b + h*32 + mo*16 + quad*4);
            const float4 bk4 = *(const float4*)(qkv_b + 192 + h*32 + mo*16 + quad*4);
            #pragma unroll
            for (int t = 0; t < 4; ++t) {
                U4 uq, uk;
                uq.u[0] = pk2((accQ[mo][t][0] + bq4.x) * SC,
                              (accQ[mo][t][1] + bq4.y) * SC);
                uq.u[1] = pk2((accQ[mo][t][2] + bq4.z) * SC,
                              (accQ[mo][t][3] + bq4.w) * SC);
                qf[t][mo] = uq.v;                   // B-frag: Q[i=t*16+c16][d]
                uk.u[0] = pk2(accK[mo][t][0] + bk4.x, accK[mo][t][1] + bk4.y);
                uk.u[1] = pk2(accK[mo][t][2] + bk4.z, accK[mo][t][3] + bk4.w);
                kf[t][mo] = uk.v;                   // A-frag: K[j=t*16+c16][d]
            }
        }
    }

    // ========== GEMM1 pass 2: V (unswapped: A=x, B=W) ======================
    // acc lane holds (tok = t*16+quad*4+r, d = dt*16+c16)
    {
        f32x4 accV[4][2] = {};
        #pragma unroll
        for (int ks = 0; ks < 6; ++ks) {
            const int c0 = ks*32 + quad*8;
            bf16x8 xf[4];
            #pragma unroll
            for (int t = 0; t < 4; ++t)
                xf[t] = *(const bf16x8*)&xs[(t*16 + c16)*200 + c0];
            #pragma unroll
            for (int dt = 0; dt < 2; ++dt) {
                const bf16x8 wv =
                    *(const bf16x8*)(w1 + (size_t)(384 + h*32 + dt*16 + c16)*192 + c0);
                #pragma unroll
                for (int t = 0; t < 4; ++t)
                    accV[t][dt] = MFMA32(xf[t], wv, accV[t][dt]);
            }
        }
        const float bv0 = qkv_b[384 + h*32 + c16];
        const float bv1 = qkv_b[384 + h*32 + 16 + c16];
        #pragma unroll
        for (int j4 = 0; j4 < 4; ++j4)
            #pragma unroll
            for (int dt = 0; dt < 2; ++dt) {
                const float bv = dt ? bv1 : bv0;
                U4 uv;
                uv.u[0] = pk2(accV[j4][dt][0] + bv, accV[j4][dt][1] + bv);
                uv.u[1] = pk2(accV[j4][dt][2] + bv, accV[j4][dt][3] + bv);
                vf[j4][dt] = uv.v;                  // B-frag: V[j][d=dt*16+c16]
            }
    }

    // ========== S^T = K @ Q^T  (+bias+mask, rolled per-jt prefetch) ========
    // S^T C-layout: lane holds (j = jt*16+quad*4+r, i = it*16+c16)
    const unsigned short* bmb = bm + ((size_t)(b & 63)*6 + h)*4096;
    f32x4 s[4][4];
    #pragma unroll
    for (int jt = 0; jt < 4; ++jt) {
        ushort4 bmv[4];
        #pragma unroll
        for (int it = 0; it < 4; ++it)
            bmv[it] = *(const ushort4*)(bmb + (jt*4 + it)*256 + lane*4);
        #pragma unroll
        for (int it = 0; it < 4; ++it) {
            f32x4 z = {0.f, 0.f, 0.f, 0.f};
            z         = MFMA16(kf[jt][0], qf[it][0], z);
            s[jt][it] = MFMA16(kf[jt][1], qf[it][1], z);
        }
        #pragma unroll
        for (int it = 0; it < 4; ++it) {
            s[jt][it][0] += b2f(bmv[it].x);
            s[jt][it][1] += b2f(bmv[it].y);
            s[jt][it][2] += b2f(bmv[it].z);
            s[jt][it][3] += b2f(bmv[it].w);
        }
    }

    // ========== softmax over j (rows of S^T, 16 in-lane + 2 shfl) ==========
    const float L2E = 1.4426950408889634f;
    #pragma unroll
    for (int it = 0; it < 4; ++it) {
        float m0 = s[0][it][0];
        #pragma unroll
        for (int jt = 0; jt < 4; ++jt)
            #pragma unroll
            for (int r = 0; r < 4; ++r)
                m0 = fmaxf(m0, s[jt][it][r]);
        m0 = fmaxf(m0, __shfl_xor(m0, 16));
        m0 = fmaxf(m0, __shfl_xor(m0, 32));
        float sum = 0.f;
        #pragma unroll
        for (int jt = 0; jt < 4; ++jt)
            #pragma unroll
            for (int r = 0; r < 4; ++r) {
                const float e = exp2f((s[jt][it][r] - m0) * L2E);
                s[jt][it][r] = e;
                sum += e;
            }
        sum += __shfl_xor(sum, 16);
        sum += __shfl_xor(sum, 32);
        const float rinv = 1.0f / sum;
        #pragma unroll
        for (int jt = 0; jt < 4; ++jt)
            #pragma unroll
            for (int r = 0; r < 4; ++r)
                s[jt][it][r] *= rinv;
    }

    // ========== attn store (float4: lane holds 4 consecutive j) ============
    float* aob = attn_out + ((size_t)b*6 + h)*4096;
    #pragma unroll
    for (int it = 0; it < 4; ++it)
        #pragma unroll
        for (int jt = 0; jt < 4; ++jt)
            *(f32x4*)(aob + (it*16 + c16)*64 + jt*16 + quad*4) = s[jt][it];

    // ========== ctx = P @ V (P packed straight from S^T regs) ==============
    f32x4 accO[4][2] = {};
    #pragma unroll
    for (int j4 = 0; j4 < 4; ++j4)
        #pragma unroll
        for (int it = 0; it < 4; ++it) {
            U4 p;
            p.u[0] = pk2(s[j4][it][0], s[j4][it][1]);
            p.u[1] = pk2(s[j4][it][2], s[j4][it][3]);
            accO[it][0] = MFMA16(p.v, vf[j4][0], accO[it][0]);
            accO[it][1] = MFMA16(p.v, vf[j4][1], accO[it][1]);
        }

    // ========== ctx -> shared LDS (cross-wave), then proj ==================
    #pragma unroll
    for (int it = 0; it < 4; ++it)
        #pragma unroll
        for (int dt = 0; dt < 2; ++dt)
            #pragma unroll
            for (int r = 0; r < 4; ++r)
                cs[(it*16 + quad*4 + r)*200 + h*32 + dt*16 + c16] =
                    (unsigned short)bfr(accO[it][dt][r]);
    __syncthreads();

    f32x4 accU[4][2] = {};
    #pragma unroll
    for (int ks = 0; ks < 6; ++ks) {
        const int c0 = ks*32 + quad*8;
        bf16x8 cf[4];
        #pragma unroll
        for (int mt = 0; mt < 4; ++mt)
            cf[mt] = *(const bf16x8*)&cs[(mt*16 + c16)*200 + c0];
        #pragma unroll
        for (int ntl = 0; ntl < 2; ++ntl) {
            const bf16x8 wf =
                *(const bf16x8*)(w2 + (size_t)((h*2 + ntl)*16 + c16)*192 + c0);
            #pragma unroll
            for (int mt = 0; mt < 4; ++mt)
                accU[mt][ntl] = MFMA32(cf[mt], wf, accU[mt][ntl]);
        }
    }
    #pragma unroll
    for (int ntl = 0; ntl < 2; ++ntl) {
        const int o = (h*2 + ntl)*16 + c16;
        const float pb2 = proj_b[o];
        #pragma unroll
        for (int mt = 0; mt < 4; ++mt)
            #pragma unroll
            for (int r = 0; r < 4; ++r)
                out[((size_t)b*64 + mt*16 + quad*4 + r)*192 + o] =
                    accU[mt][ntl][r] + pb2;
    }
}

// ---------------------------------------------------------------------------
extern "C" void kernel_launch(void* const* d_in, const int* in_sizes, int n_in,
                              void* d_out, int out_size, void* d_ws, size_t ws_size,
                              hipStream_t stream) {
    const float* x      = (const float*)d_in[0];
    const float* mask   = (const float*)d_in[1];
    const float* qkv_w  = (const float*)d_in[2];
    const float* qkv_b  = (const float*)d_in[3];
    const float* proj_w = (const float*)d_in[4];
    const float* proj_b = (const float*)d_in[5];
    const float* table  = (const float*)d_in[6];

    if (ws_size < WS_NEEDED) return;   // ~3.5 MB scratch required

    unsigned short* w1 = (unsigned short*)d_ws;
    unsigned short* w2 = (unsigned short*)((char*)d_ws + W2_OFF);
    unsigned short* bm = (unsigned short*)((char*)d_ws + BM_OFF);

    float* out  = (float*)d_out;
    float* attn = out + (size_t)4096 * 64 * 192;

    hipLaunchKernelGGL(wa_prep_w,  dim3(576),  dim3(256), 0, stream,
                       qkv_w, proj_w, w1, w2);
    hipLaunchKernelGGL(wa_prep_bm, dim3(1536), dim3(256), 0, stream,
                       mask, table, bm);
    hipLaunchKernelGGL(wa_main, dim3(4096), dim3(384), 0, stream,
                       x, qkv_b, proj_b, w1, w2, bm, out, attn);
}